// Round 1
// baseline (96.245 us; speedup 1.0000x reference)
//
#include <hip/hip_runtime.h>
#include <hip/hip_bf16.h>

// GraphSAGE 2-layer forward, fp32.
// B=512, S0=25, S1=10, IN_DIM=256, HID=128 (concat->256), N_CLASSES=7.

constexpr int IN   = 256;
constexpr int HIDC = 128;   // per-branch hidden
constexpr int BM   = 16;    // rows per block in k_h1
constexpr int ROWS1 = 512 * 25;  // 12800

// ---------------- Kernel 1: h1 = relu([f1@Wx1+b, mean10(f2)@Wn1+b]) --------
// One block = BM rows. LDS: a0 = f1 rows, a1 = mean-of-10 f2 rows.
// Compute: 256 threads; thread t -> cols {2j,2j+1} (j=t&127), rows g*8..g*8+7 (g=t>>7).
__global__ __launch_bounds__(256) void k_h1(
    const int* __restrict__ ids1, const int* __restrict__ ids2,
    const float* __restrict__ feats,
    const float* __restrict__ Wx, const float* __restrict__ bx,
    const float* __restrict__ Wn, const float* __restrict__ bn,
    float* __restrict__ h1)
{
    __shared__ float a0[BM][IN];
    __shared__ float a1[BM][IN];
    const int tid = threadIdx.x;
    const int r0  = blockIdx.x * BM;

    // ---- staging: each row staged by 64 threads in float4 (coalesced 1KB/row)
    const int sub = tid & 63;      // float4 index within row
    const int rg  = tid >> 6;      // 0..3
    #pragma unroll
    for (int i = 0; i < BM; i += 4) {
        const int rr = rg + i;
        const int r  = r0 + rr;
        const float4* s0 = (const float4*)(feats + (size_t)ids1[r] * IN);
        ((float4*)a0[rr])[sub] = s0[sub];
        float4 acc = make_float4(0.f, 0.f, 0.f, 0.f);
        #pragma unroll
        for (int kk = 0; kk < 10; ++kk) {
            const float4* p = (const float4*)(feats + (size_t)ids2[r * 10 + kk] * IN);
            const float4 v = p[sub];
            acc.x += v.x; acc.y += v.y; acc.z += v.z; acc.w += v.w;
        }
        acc.x *= 0.1f; acc.y *= 0.1f; acc.z *= 0.1f; acc.w *= 0.1f;
        ((float4*)a1[rr])[sub] = acc;
    }
    __syncthreads();

    // ---- compute: register-tiled GEMV, 8 rows x 2 cols per thread
    const int j  = tid & 127;
    const int g  = tid >> 7;            // row group
    const int c0 = 2 * j;               // output col pair {c0, c0+1} in [0,256)
    const bool nb = (c0 >= HIDC);       // neighbor branch?
    const int cc  = c0 & (HIDC - 1);
    const float* __restrict__ W  = nb ? Wn : Wx;
    const float  b0 = (nb ? bn : bx)[cc];
    const float  b1 = (nb ? bn : bx)[cc + 1];
    const float (* __restrict__ A)[IN] = nb ? a1 : a0;
    const float2* __restrict__ W2 = (const float2*)W;  // W[k*128+cc] -> W2[k*64 + cc/2]
    const int w2i = cc >> 1;

    float acc0[8], acc1[8];
    #pragma unroll
    for (int rr = 0; rr < 8; ++rr) { acc0[rr] = 0.f; acc1[rr] = 0.f; }

    for (int k = 0; k < IN; k += 4) {
        float4 av[8];
        #pragma unroll
        for (int rr = 0; rr < 8; ++rr)
            av[rr] = *(const float4*)&A[g * 8 + rr][k];   // wave-uniform -> broadcast
        #pragma unroll
        for (int kk = 0; kk < 4; ++kk) {
            const float2 w = W2[(size_t)(k + kk) * 64 + w2i];
            #pragma unroll
            for (int rr = 0; rr < 8; ++rr) {
                const float a = (&av[rr].x)[kk];
                acc0[rr] = fmaf(a, w.x, acc0[rr]);
                acc1[rr] = fmaf(a, w.y, acc1[rr]);
            }
        }
    }
    #pragma unroll
    for (int rr = 0; rr < 8; ++rr) {
        const int r = r0 + g * 8 + rr;
        float2 v;
        v.x = fmaxf(acc0[rr] + b0, 0.f);
        v.y = fmaxf(acc1[rr] + b1, 0.f);
        *(float2*)&h1[(size_t)r * (2 * HIDC) + c0] = v;
    }
}

// ---------------- Kernel 2: per output row -----------------------------------
// h0 = relu([f0@Wx1+b, mean25(f1)@Wn1+b]); g0 = [h0@Wx2+b, mean25(h1)@Wn2+b];
// out = normalize(g0) @ Wfc + bfc
__global__ __launch_bounds__(256) void k_out(
    const int* __restrict__ ids, const int* __restrict__ ids1,
    const float* __restrict__ feats, const float* __restrict__ h1,
    const float* __restrict__ Wx1, const float* __restrict__ bx1,
    const float* __restrict__ Wn1, const float* __restrict__ bn1,
    const float* __restrict__ Wx2, const float* __restrict__ bx2,
    const float* __restrict__ Wn2, const float* __restrict__ bn2,
    const float* __restrict__ Wfc, const float* __restrict__ bfc,
    float* __restrict__ out)
{
    __shared__ float x0[IN];
    __shared__ float m1[IN];
    __shared__ float mh[IN];
    __shared__ float h0[IN];
    __shared__ float nred[4];
    __shared__ float fcred[7][4];
    const int i   = blockIdx.x;
    const int tid = threadIdx.x;

    // stage: f0 row, mean of 25 f1 rows, mean of 25 h1 rows (col = tid, coalesced)
    x0[tid] = feats[(size_t)ids[i] * IN + tid];
    float s = 0.f, sh = 0.f;
    for (int kk = 0; kk < 25; ++kk) {
        const int r = i * 25 + kk;
        s  += feats[(size_t)ids1[r] * IN + tid];
        sh += h1[(size_t)r * IN + tid];
    }
    m1[tid] = s  * 0.04f;
    mh[tid] = sh * 0.04f;
    __syncthreads();

    const int  j  = tid & 127;
    const bool nb = (tid >= 128);
    // layer 1
    {
        const float* __restrict__ W = nb ? Wn1 : Wx1;
        const float* __restrict__ X = nb ? m1 : x0;
        float acc = (nb ? bn1 : bx1)[j];
        #pragma unroll 4
        for (int k = 0; k < IN; ++k) acc = fmaf(X[k], W[(size_t)k * HIDC + j], acc);
        h0[tid] = fmaxf(acc, 0.f);
    }
    __syncthreads();
    // layer 2 (no activation)
    float g;
    {
        const float* __restrict__ W = nb ? Wn2 : Wx2;
        const float* __restrict__ X = nb ? mh : h0;
        float acc = (nb ? bn2 : bx2)[j];
        #pragma unroll 4
        for (int k = 0; k < IN; ++k) acc = fmaf(X[k], W[(size_t)k * HIDC + j], acc);
        g = acc;
    }
    // L2 norm over the 256 g0 values (one per thread)
    float sq = g * g;
    #pragma unroll
    for (int off = 32; off > 0; off >>= 1) sq += __shfl_down(sq, off);
    if ((tid & 63) == 0) nred[tid >> 6] = sq;
    __syncthreads();
    const float total = nred[0] + nred[1] + nred[2] + nred[3];
    const float inv = 1.f / fmaxf(sqrtf(total), 1e-12f);
    const float p = g * inv;   // normalized g0[tid]

    // fc: out[c] = b_fc[c] + sum_k p[k] * Wfc[k*7+c]
    #pragma unroll
    for (int c = 0; c < 7; ++c) {
        float t = p * Wfc[(size_t)tid * 7 + c];
        #pragma unroll
        for (int off = 32; off > 0; off >>= 1) t += __shfl_down(t, off);
        if ((tid & 63) == 0) fcred[c][tid >> 6] = t;
    }
    __syncthreads();
    if (tid < 7) {
        out[(size_t)i * 7 + tid] =
            fcred[tid][0] + fcred[tid][1] + fcred[tid][2] + fcred[tid][3] + bfc[tid];
    }
}

extern "C" void kernel_launch(void* const* d_in, const int* in_sizes, int n_in,
                              void* d_out, int out_size, void* d_ws, size_t ws_size,
                              hipStream_t stream) {
    const int*   ids   = (const int*)d_in[0];
    const int*   ids1  = (const int*)d_in[1];
    const int*   ids2  = (const int*)d_in[2];
    const float* feats = (const float*)d_in[3];
    const float* Wx1   = (const float*)d_in[4];
    const float* bx1   = (const float*)d_in[5];
    const float* Wn1   = (const float*)d_in[6];
    const float* bn1   = (const float*)d_in[7];
    const float* Wx2   = (const float*)d_in[8];
    const float* bx2   = (const float*)d_in[9];
    const float* Wn2   = (const float*)d_in[10];
    const float* bn2   = (const float*)d_in[11];
    const float* Wfc   = (const float*)d_in[12];
    const float* bfc   = (const float*)d_in[13];
    float* out = (float*)d_out;
    float* h1  = (float*)d_ws;   // 12800 x 256 f32 = 13.1 MB

    k_h1<<<ROWS1 / BM, 256, 0, stream>>>(ids1, ids2, feats, Wx1, bx1, Wn1, bn1, h1);
    k_out<<<512, 256, 0, stream>>>(ids, ids1, feats, h1,
                                   Wx1, bx1, Wn1, bn1,
                                   Wx2, bx2, Wn2, bn2,
                                   Wfc, bfc, out);
}